// Round 6
// baseline (206.508 us; speedup 1.0000x reference)
//
#include <hip/hip_runtime.h>

// BitDelta chained layers: per layer W = base + bd*mask (4096x4096 fp32),
// x = x @ W, x [16,4096].  Weight-streaming, memory-bound (134 MB/layer).
//
// Stage 1 (per layer): grid 512 = (KCHUNKS=32) x (NCHUNKS=16), TPB=256
// (4 waves).  Wave owns KW=32 k-rows; lane owns VEC=4 cols (float4 = 1 KB
// per wave-instruction).  DEPTH-3 window prefetch: 12 float4 loads in
// flight per wave via fresh-SSA temporaries + copy rotation (no ring).
// x read via wave-uniform scalar loads (no LDS, no syncs in k-loop).
// 4-wave LDS reduce; wave 0 writes block partial to d_ws (no atomics).
// Stage 2: 64-block kernel folds the 32 k-partials into the output.

#define DD 4096
#define BB 16
#define KW 32                  // k-rows per wave
#define NW 4                   // waves per block
#define KC (KW * NW)           // 128 k-rows per block
#define VEC 4
#define CT 256                 // cols per block (64 lanes * 4)
#define TPB 256
#define KCHUNKS (DD / KC)      // 32
#define NCHUNKS (DD / CT)      // 16
#define OUT_ELEMS (BB * DD)    // 65536

typedef float f32x4 __attribute__((ext_vector_type(4)));   // native vec for builtins

struct Win { f32x4 b0, b1, m0, m1; };   // one 2-row window of base+mask

__device__ __forceinline__ Win load_win(const float* __restrict__ wb,
                                        const float* __restrict__ wm,
                                        int kw) {
    Win w;
    w.b0 = __builtin_nontemporal_load(
        reinterpret_cast<const f32x4*>(wb + (size_t)kw * DD));
    w.b1 = __builtin_nontemporal_load(
        reinterpret_cast<const f32x4*>(wb + (size_t)(kw + 1) * DD));
    w.m0 = __builtin_nontemporal_load(
        reinterpret_cast<const f32x4*>(wm + (size_t)kw * DD));
    w.m1 = __builtin_nontemporal_load(
        reinterpret_cast<const f32x4*>(wm + (size_t)(kw + 1) * DD));
    return w;
}

__global__ __launch_bounds__(TPB)
void bitdelta_layer(const float* __restrict__ x,
                    const float* __restrict__ base,
                    const float* __restrict__ mask,
                    const float* __restrict__ bitdelta,
                    int layer,
                    float* __restrict__ part) {
    __shared__ float red[16][3 * 64];   // 12 KB reduce buffer

    const int tid = threadIdx.x;
    const int l   = tid & 63;
    const int wid = __builtin_amdgcn_readfirstlane(tid >> 6);  // wave-uniform

    const int bid    = blockIdx.x;
    const int cchunk = bid & (NCHUNKS - 1);
    const int kchunk = bid >> 4;              // bid / NCHUNKS

    const int c0 = cchunk * CT + l * VEC;
    const int k0 = kchunk * KC + wid * KW;    // wave-uniform

    const float bd = bitdelta[layer];

    const float* wb = base + (size_t)k0 * DD + c0;
    const float* wm = mask + (size_t)k0 * DD + c0;
    const float* xp = x + k0;                 // wave-uniform base

    float acc[BB][VEC];
#pragma unroll
    for (int r = 0; r < BB; ++r)
#pragma unroll
        for (int c = 0; c < VEC; ++c) acc[r][c] = 0.0f;

    // Prologue: windows 0,1,2 in flight (12 float4 loads).
    Win w0 = load_win(wb, wm, 0);
    Win w1 = load_win(wb, wm, 2);
    Win w2 = load_win(wb, wm, 4);

#pragma unroll
    for (int kw = 0; kw < KW; kw += 2) {
        // Issue window kw+6 FIRST (keeps 3 windows in flight at the wait).
        Win nw;
        if (kw + 6 < KW) nw = load_win(wb, wm, kw + 6);
        else             nw = w2;   // tail: value never consumed

        const float g00 = fmaf(bd, w0.m0[0], w0.b0[0]);
        const float g01 = fmaf(bd, w0.m0[1], w0.b0[1]);
        const float g02 = fmaf(bd, w0.m0[2], w0.b0[2]);
        const float g03 = fmaf(bd, w0.m0[3], w0.b0[3]);
        const float g10 = fmaf(bd, w0.m1[0], w0.b1[0]);
        const float g11 = fmaf(bd, w0.m1[1], w0.b1[1]);
        const float g12 = fmaf(bd, w0.m1[2], w0.b1[2]);
        const float g13 = fmaf(bd, w0.m1[3], w0.b1[3]);

#pragma unroll
        for (int r = 0; r < BB; ++r) {
            // Wave-uniform -> scalar loads on the SMEM pipe.
            const float xv0 = xp[r * DD + kw];
            const float xv1 = xp[r * DD + kw + 1];
            acc[r][0] = fmaf(xv0, g00, acc[r][0]);
            acc[r][1] = fmaf(xv0, g01, acc[r][1]);
            acc[r][2] = fmaf(xv0, g02, acc[r][2]);
            acc[r][3] = fmaf(xv0, g03, acc[r][3]);
            acc[r][0] = fmaf(xv1, g10, acc[r][0]);
            acc[r][1] = fmaf(xv1, g11, acc[r][1]);
            acc[r][2] = fmaf(xv1, g12, acc[r][2]);
            acc[r][3] = fmaf(xv1, g13, acc[r][3]);
        }

        // Copy-rotation (pure SSA renaming after full unroll).
        w0 = w1; w1 = w2; w2 = nw;
    }

    // 4-wave LDS reduce, four rounds of 16 elements (12 KB, conflict-free).
#pragma unroll
    for (int t = 0; t < 4; ++t) {
        if (t) __syncthreads();
        if (wid != 0) {
#pragma unroll
            for (int e = 0; e < 16; ++e) {
                const int r = t * 4 + (e >> 2), c = e & 3;
                red[e][(wid - 1) * 64 + l] = acc[r][c];
            }
        }
        __syncthreads();
        if (wid == 0) {
#pragma unroll
            for (int e = 0; e < 16; ++e) {
                const int r = t * 4 + (e >> 2), c = e & 3;
                acc[r][c] += red[e][l] + red[e][64 + l] + red[e][128 + l];
            }
        }
    }

    // Wave 0 writes the block partial: [16][256] slab, float4 stores.
    if (wid == 0) {
        float* pp = part + (size_t)kchunk * OUT_ELEMS;
#pragma unroll
        for (int r = 0; r < BB; ++r) {
            f32x4 v = { acc[r][0], acc[r][1], acc[r][2], acc[r][3] };
            *reinterpret_cast<f32x4*>(&pp[r * DD + c0]) = v;
        }
    }
}

// Stage 2: out[e] = sum_k part[k][e].  64 blocks x 256 threads x float4.
__global__ __launch_bounds__(256)
void reduce_partials(const float* __restrict__ part, float* __restrict__ out) {
    const int idx = (blockIdx.x * 256 + threadIdx.x) * 4;
    f32x4 a = *reinterpret_cast<const f32x4*>(&part[idx]);
#pragma unroll
    for (int k = 1; k < KCHUNKS; ++k) {
        const f32x4 p = *reinterpret_cast<const f32x4*>(
            &part[(size_t)k * OUT_ELEMS + idx]);
        a += p;
    }
    *reinterpret_cast<f32x4*>(&out[idx]) = a;
}

extern "C" void kernel_launch(void* const* d_in, const int* in_sizes, int n_in,
                              void* d_out, int out_size, void* d_ws, size_t ws_size,
                              hipStream_t stream) {
    const float* x    = (const float*)d_in[0];   // [16,4096]
    const float* base = (const float*)d_in[1];   // [4,4096,4096]
    const float* mask = (const float*)d_in[2];   // [4,4096,4096]
    const float* bd   = (const float*)d_in[3];   // [4]
    float* out = (float*)d_out;                  // [16,4096] fp32

    float* part = (float*)d_ws;                  // 32 x 65536 floats = 8 MB
    float* y0   = part + (size_t)KCHUNKS * OUT_ELEMS;
    float* y1   = y0 + OUT_ELEMS;

    const size_t layer_stride = (size_t)DD * DD;
    const int    grid1 = KCHUNKS * NCHUNKS;      // 512
    const int    grid2 = OUT_ELEMS / (256 * 4);  // 64

    bitdelta_layer<<<grid1, TPB, 0, stream>>>(x, base, mask, bd, 0, part);
    reduce_partials<<<grid2, 256, 0, stream>>>(part, y0);

    bitdelta_layer<<<grid1, TPB, 0, stream>>>(y0, base + 1 * layer_stride,
                                              mask + 1 * layer_stride, bd, 1, part);
    reduce_partials<<<grid2, 256, 0, stream>>>(part, y1);

    bitdelta_layer<<<grid1, TPB, 0, stream>>>(y1, base + 2 * layer_stride,
                                              mask + 2 * layer_stride, bd, 2, part);
    reduce_partials<<<grid2, 256, 0, stream>>>(part, y0);

    bitdelta_layer<<<grid1, TPB, 0, stream>>>(y0, base + 3 * layer_stride,
                                              mask + 3 * layer_stride, bd, 3, part);
    reduce_partials<<<grid2, 256, 0, stream>>>(part, out);
}

// Round 7
// 152.516 us; speedup vs baseline: 1.3540x; 1.3540x over previous
//
#include <hip/hip_runtime.h>

// BitDelta chained layers: per layer W = base + bd*mask (4096x4096 fp32),
// x = x @ W, x [16,4096].  Weight-streaming, memory-bound (134 MB/layer).
//
// Stage 1 (per layer): grid 1024 = (KCHUNKS=64) x (NCHUNKS=16), TPB=256
// (4 waves) -> 4 blocks/CU = 4 waves/SIMD.  Wave owns KW=16 k-rows; lane
// owns VEC=4 cols (float4 = 1 KB/wave-instruction).  Depth-1 window
// prefetch (R4-proven).  x via wave-uniform scalar loads (no LDS/syncs in
// k-loop).  4-wave LDS reduce; wave 0 writes block partial (no atomics).
// Stage 2: 64-block kernel folds the 64 k-partials into the output.

#define DD 4096
#define BB 16
#define KW 16                  // k-rows per wave
#define NW 4                   // waves per block
#define KC (KW * NW)           // 64 k-rows per block
#define VEC 4
#define CT 256                 // cols per block (64 lanes * 4)
#define TPB 256
#define KCHUNKS (DD / KC)      // 64
#define NCHUNKS (DD / CT)      // 16
#define OUT_ELEMS (BB * DD)    // 65536

__global__ __launch_bounds__(TPB)
void bitdelta_layer(const float* __restrict__ x,
                    const float* __restrict__ base,
                    const float* __restrict__ mask,
                    const float* __restrict__ bitdelta,
                    int layer,
                    float* __restrict__ part) {
    __shared__ float red[16][3 * 64];   // 12 KB reduce buffer

    const int tid = threadIdx.x;
    const int l   = tid & 63;
    const int wid = __builtin_amdgcn_readfirstlane(tid >> 6);  // wave-uniform

    const int bid    = blockIdx.x;
    const int cchunk = bid & (NCHUNKS - 1);
    const int kchunk = bid >> 4;              // bid / NCHUNKS

    const int c0 = cchunk * CT + l * VEC;
    const int k0 = kchunk * KC + wid * KW;    // wave-uniform

    const float bd = bitdelta[layer];

    const float* wb = base + (size_t)k0 * DD + c0;
    const float* wm = mask + (size_t)k0 * DD + c0;
    const float* xp = x + k0;                 // wave-uniform base

    float acc[BB][VEC];
#pragma unroll
    for (int r = 0; r < BB; ++r)
#pragma unroll
        for (int c = 0; c < VEC; ++c) acc[r][c] = 0.0f;

    // Window 0 (2 k-rows): float4 loads = 1 KB/wave-instruction.
    float4 b0 = *reinterpret_cast<const float4*>(wb);
    float4 b1 = *reinterpret_cast<const float4*>(wb + DD);
    float4 m0 = *reinterpret_cast<const float4*>(wm);
    float4 m1 = *reinterpret_cast<const float4*>(wm + DD);

#pragma unroll
    for (int kw = 0; kw < KW; kw += 2) {
        float4 nb0, nb1, nm0, nm1;
        if (kw + 2 < KW) {   // compile-time after full unroll
            const float* pb = wb + (size_t)(kw + 2) * DD;
            const float* pm = wm + (size_t)(kw + 2) * DD;
            nb0 = *reinterpret_cast<const float4*>(pb);
            nb1 = *reinterpret_cast<const float4*>(pb + DD);
            nm0 = *reinterpret_cast<const float4*>(pm);
            nm1 = *reinterpret_cast<const float4*>(pm + DD);
        }

        const float w00 = fmaf(bd, m0.x, b0.x);
        const float w01 = fmaf(bd, m0.y, b0.y);
        const float w02 = fmaf(bd, m0.z, b0.z);
        const float w03 = fmaf(bd, m0.w, b0.w);
        const float w10 = fmaf(bd, m1.x, b1.x);
        const float w11 = fmaf(bd, m1.y, b1.y);
        const float w12 = fmaf(bd, m1.z, b1.z);
        const float w13 = fmaf(bd, m1.w, b1.w);

#pragma unroll
        for (int r = 0; r < BB; ++r) {
            // Wave-uniform -> scalar loads on the SMEM pipe.
            const float xv0 = xp[r * DD + kw];
            const float xv1 = xp[r * DD + kw + 1];
            acc[r][0] = fmaf(xv0, w00, acc[r][0]);
            acc[r][1] = fmaf(xv0, w01, acc[r][1]);
            acc[r][2] = fmaf(xv0, w02, acc[r][2]);
            acc[r][3] = fmaf(xv0, w03, acc[r][3]);
            acc[r][0] = fmaf(xv1, w10, acc[r][0]);
            acc[r][1] = fmaf(xv1, w11, acc[r][1]);
            acc[r][2] = fmaf(xv1, w12, acc[r][2]);
            acc[r][3] = fmaf(xv1, w13, acc[r][3]);
        }

        if (kw + 2 < KW) { b0 = nb0; b1 = nb1; m0 = nm0; m1 = nm1; }
    }

    // 4-wave LDS reduce, four rounds of 16 elements (12 KB, conflict-free).
#pragma unroll
    for (int t = 0; t < 4; ++t) {
        if (t) __syncthreads();
        if (wid != 0) {
#pragma unroll
            for (int e = 0; e < 16; ++e) {
                const int r = t * 4 + (e >> 2), c = e & 3;
                red[e][(wid - 1) * 64 + l] = acc[r][c];
            }
        }
        __syncthreads();
        if (wid == 0) {
#pragma unroll
            for (int e = 0; e < 16; ++e) {
                const int r = t * 4 + (e >> 2), c = e & 3;
                acc[r][c] += red[e][l] + red[e][64 + l] + red[e][128 + l];
            }
        }
    }

    // Wave 0 writes the block partial: [16][256] slab, float4 stores.
    if (wid == 0) {
        float* pp = part + (size_t)kchunk * OUT_ELEMS;
#pragma unroll
        for (int r = 0; r < BB; ++r) {
            const float4 v = make_float4(acc[r][0], acc[r][1], acc[r][2], acc[r][3]);
            *reinterpret_cast<float4*>(&pp[r * DD + c0]) = v;
        }
    }
}

// Stage 2: out[e] = sum_k part[k][e].  64 blocks x 256 threads x float4.
__global__ __launch_bounds__(256)
void reduce_partials(const float* __restrict__ part, float* __restrict__ out) {
    const int idx = (blockIdx.x * 256 + threadIdx.x) * 4;
    float4 a = *reinterpret_cast<const float4*>(&part[idx]);
#pragma unroll
    for (int k = 1; k < KCHUNKS; ++k) {
        const float4 p = *reinterpret_cast<const float4*>(
            &part[(size_t)k * OUT_ELEMS + idx]);
        a.x += p.x; a.y += p.y; a.z += p.z; a.w += p.w;
    }
    *reinterpret_cast<float4*>(&out[idx]) = a;
}

extern "C" void kernel_launch(void* const* d_in, const int* in_sizes, int n_in,
                              void* d_out, int out_size, void* d_ws, size_t ws_size,
                              hipStream_t stream) {
    const float* x    = (const float*)d_in[0];   // [16,4096]
    const float* base = (const float*)d_in[1];   // [4,4096,4096]
    const float* mask = (const float*)d_in[2];   // [4,4096,4096]
    const float* bd   = (const float*)d_in[3];   // [4]
    float* out = (float*)d_out;                  // [16,4096] fp32

    float* part = (float*)d_ws;                  // 64 x 65536 floats = 16 MB
    float* y0   = part + (size_t)KCHUNKS * OUT_ELEMS;
    float* y1   = y0 + OUT_ELEMS;

    const size_t layer_stride = (size_t)DD * DD;
    const int    grid1 = KCHUNKS * NCHUNKS;      // 1024
    const int    grid2 = OUT_ELEMS / (256 * 4);  // 64

    bitdelta_layer<<<grid1, TPB, 0, stream>>>(x, base, mask, bd, 0, part);
    reduce_partials<<<grid2, 256, 0, stream>>>(part, y0);

    bitdelta_layer<<<grid1, TPB, 0, stream>>>(y0, base + 1 * layer_stride,
                                              mask + 1 * layer_stride, bd, 1, part);
    reduce_partials<<<grid2, 256, 0, stream>>>(part, y1);

    bitdelta_layer<<<grid1, TPB, 0, stream>>>(y1, base + 2 * layer_stride,
                                              mask + 2 * layer_stride, bd, 2, part);
    reduce_partials<<<grid2, 256, 0, stream>>>(part, y0);

    bitdelta_layer<<<grid1, TPB, 0, stream>>>(y0, base + 3 * layer_stride,
                                              mask + 3 * layer_stride, bd, 3, part);
    reduce_partials<<<grid2, 256, 0, stream>>>(part, out);
}